// Round 1
// baseline (155.596 us; speedup 1.0000x reference)
//
#include <hip/hip_runtime.h>
#include <hip/hip_bf16.h>
#include <stdint.h>

// Problem constants
#define Bb 4
#define Nn 4096
#define Kk 16
#define Cc 128
#define Hh 256
#define BN 16384  // B*N

typedef __attribute__((ext_vector_type(4))) float f32x4;
typedef __attribute__((ext_vector_type(8))) short s16x8;

__device__ __forceinline__ unsigned short f2bf(float f) {
  union { float f; unsigned u; } v; v.f = f;
  unsigned r = v.u + 0x7FFFu + ((v.u >> 16) & 1u);
  return (unsigned short)(r >> 16);
}
__device__ __forceinline__ float bf2f(unsigned short s) {
  union { unsigned u; float f; } v; v.u = ((unsigned)s) << 16;
  return v.f;
}
__device__ __forceinline__ s16x8 ld16(const unsigned short* p) {
  return *(const s16x8*)p;
}

#define MFMA16(a, b, c) __builtin_amdgcn_mfma_f32_16x16x32_bf16((a), (b), (c), 0, 0, 0)

// ---------------------------------------------------------------------------
// pack_kernel: feats f32->bf16, and pre-pack W1cat/W2/W3 into MFMA-fragment-
// major bf16 layout so GEMM B-operand loads are 16B/lane fully coalesced.
// Fragment (kt, ct, lane l, elem j) <- W[kt*32 + (l>>4)*8 + j][ct*16 + (l&15)]
// ---------------------------------------------------------------------------
__global__ void pack_kernel(const float* __restrict__ feats,
                            const float* __restrict__ W1,
                            const float* __restrict__ W2,
                            const float* __restrict__ W3,
                            unsigned short* __restrict__ featsb,
                            unsigned short* __restrict__ W1p,
                            unsigned short* __restrict__ W2p,
                            unsigned short* __restrict__ W3p) {
  int blk = blockIdx.x, t = threadIdx.x;
  if (blk < 1024) {
    // feats: 16384*128 = 2,097,152 f32 -> bf16, 8 per thread
    int i = (blk * 256 + t) * 8;
    const float4* fp = (const float4*)(feats + i);
    float4 f0 = fp[0], f1 = fp[1];
    uint4 o;
    o.x = (unsigned)f2bf(f0.x) | ((unsigned)f2bf(f0.y) << 16);
    o.y = (unsigned)f2bf(f0.z) | ((unsigned)f2bf(f0.w) << 16);
    o.z = (unsigned)f2bf(f1.x) | ((unsigned)f2bf(f1.y) << 16);
    o.w = (unsigned)f2bf(f1.z) | ((unsigned)f2bf(f1.w) << 16);
    *(uint4*)(featsb + i) = o;
  } else if (blk < 1056) {
    // W1p: K=128, Ncols=512 (cols 0..255 = W1_top, 256..511 = W1_bot)
    int f = (blk - 1024) * 256 + t;            // 0..8191 fragment-rows
    int l = f & 63, ct = (f >> 6) & 31, kt = f >> 11;
    int col = ct * 16 + (l & 15);
    int k0 = kt * 32 + ((l >> 4) << 3);
    unsigned short tmp[8];
#pragma unroll
    for (int j = 0; j < 8; ++j) {
      int k = k0 + j;
      float v = (col < 256) ? W1[k * 256 + col]
                            : W1[(128 + k) * 256 + (col - 256)];
      tmp[j] = f2bf(v);
    }
    *(uint4*)(W1p + f * 8) = *(uint4*)tmp;
  } else if (blk < 1088) {
    // W2p: 256x256
    int f = (blk - 1056) * 256 + t;            // 0..8191
    int l = f & 63, ct = (f >> 6) & 15, kt = f >> 10;
    int col = ct * 16 + (l & 15);
    int k0 = kt * 32 + ((l >> 4) << 3);
    unsigned short tmp[8];
#pragma unroll
    for (int j = 0; j < 8; ++j) tmp[j] = f2bf(W2[(k0 + j) * 256 + col]);
    *(uint4*)(W2p + f * 8) = *(uint4*)tmp;
  } else {
    // W3p: 256x128
    int f = (blk - 1088) * 256 + t;            // 0..4095
    int l = f & 63, ct = (f >> 6) & 7, kt = f >> 9;
    int col = ct * 16 + (l & 15);
    int k0 = kt * 32 + ((l >> 4) << 3);
    unsigned short tmp[8];
#pragma unroll
    for (int j = 0; j < 8; ++j) tmp[j] = f2bf(W3[(k0 + j) * 128 + col]);
    *(uint4*)(W3p + f * 8) = *(uint4*)tmp;
  }
}

// ---------------------------------------------------------------------------
// k1: per-node precompute  A = feats@W1_top + b1  (cols 0..255)
//                          Bc = feats@W1_bot      (cols 256..511)
// GEMM M=16384, N=512, K=128, bf16 in/out, fp32 accum.
// One workgroup: 64 rows x 512 cols; wave w -> cols [w*128, w*128+128).
// ---------------------------------------------------------------------------
__global__ __launch_bounds__(256, 2) void k1_gemm(
    const unsigned short* __restrict__ featsb,
    const unsigned short* __restrict__ W1p,
    const float* __restrict__ b1,
    unsigned short* __restrict__ A_ws,
    unsigned short* __restrict__ B_ws) {
  int m0 = blockIdx.x * 64;
  int t = threadIdx.x, w = t >> 6, l = t & 63;
  int lr = l & 15, lg = l >> 4;
  f32x4 zero4 = {0.f, 0.f, 0.f, 0.f};
  f32x4 acc[4][8];
#pragma unroll
  for (int i = 0; i < 4; ++i)
#pragma unroll
    for (int j = 0; j < 8; ++j) acc[i][j] = zero4;

  for (int kt = 0; kt < 4; ++kt) {
    s16x8 a[4];
#pragma unroll
    for (int rt = 0; rt < 4; ++rt)
      a[rt] = ld16(featsb + (m0 + rt * 16 + lr) * 128 + kt * 32 + lg * 8);
#pragma unroll
    for (int ctl = 0; ctl < 8; ++ctl) {
      int ct = w * 8 + ctl;
      s16x8 bf = ld16(W1p + (((kt * 32 + ct) * 64) + l) * 8);
#pragma unroll
      for (int rt = 0; rt < 4; ++rt)
        acc[rt][ctl] = MFMA16(a[rt], bf, acc[rt][ctl]);
    }
  }
  // epilogue: C/D layout col = l&15, row = (l>>4)*4 + reg (m89-verified)
#pragma unroll
  for (int ctl = 0; ctl < 8; ++ctl) {
    int n = w * 128 + ctl * 16 + lr;
    float bias = (n < 256) ? b1[n] : 0.f;
    unsigned short* dst = (n < 256) ? (A_ws + n) : (B_ws + (n - 256));
#pragma unroll
    for (int rt = 0; rt < 4; ++rt) {
#pragma unroll
      for (int reg = 0; reg < 4; ++reg) {
        int row = m0 + rt * 16 + lg * 4 + reg;
        dst[row * 256] = f2bf(acc[rt][ctl][reg] + bias);
      }
    }
  }
}

// ---------------------------------------------------------------------------
// k2: fused edge MLP. One workgroup = 8 queries x 16 neighbors = 128 edges.
//  1) stage h1[128][256] = relu(A[q] + Bc[idx]) into XOR-swizzled LDS (bf16)
//  2) h2 = relu(h1 @ W2 + b2); fused mask + reduce over the 16 rows of each
//     row-tile (row-tile == one query) -> g[8][256] in LDS
//  3) out = g @ W3 + nvalid*b3   (tiny GEMM, rows 8..15 padding/garbage)
// ---------------------------------------------------------------------------
__global__ __launch_bounds__(256, 2) void k2_fused(
    const unsigned short* __restrict__ A_ws,
    const unsigned short* __restrict__ B_ws,
    const unsigned short* __restrict__ W2p,
    const unsigned short* __restrict__ W3p,
    const int* __restrict__ n_idxs,
    const int* __restrict__ valid,
    const float* __restrict__ b2,
    const float* __restrict__ b3,
    float* __restrict__ out) {
  __shared__ unsigned short h1s[128 * 256];  // 64 KB, swizzled
  __shared__ unsigned short gs[16 * 256];    // 8 KB, swizzled (rows 8..15 pad)
  __shared__ float validf[128];
  __shared__ float nvalidf[8];
  char* h1b = (char*)h1s;
  char* gb = (char*)gs;

  int wg = blockIdx.x, t = threadIdx.x;
  int w = t >> 6, l = t & 63, lr = l & 15, lg = l >> 4;
  int qbase = wg * 8;                 // flat query index base
  int bN = (qbase >> 12) << 12;       // batch * N  (8 | 4096, no straddle)
  int ebase = wg * 128;               // flat edge base

  if (t < 128) validf[t] = (float)valid[ebase + t];

  // ---- stage h1 ----
#pragma unroll
  for (int i = 0; i < 16; ++i) {
    int c = i * 256 + t;              // 4096 chunks of 8 bf16
    int r = c >> 5, cc = c & 31;
    int nb = n_idxs[ebase + r];
    s16x8 av = ld16(A_ws + (qbase + (r >> 4)) * 256 + cc * 8);
    s16x8 bv = ld16(B_ws + (bN + nb) * 256 + cc * 8);
    s16x8 hv;
#pragma unroll
    for (int j = 0; j < 8; ++j) {
      float v = bf2f((unsigned short)av[j]) + bf2f((unsigned short)bv[j]);
      hv[j] = (short)f2bf(fmaxf(v, 0.f));
    }
    int off = (r * 512 + cc * 16) ^ ((r & 7) << 4);
    *(s16x8*)(h1b + off) = hv;
  }
  __syncthreads();
  if (t < 8) {
    float s = 0.f;
    for (int k = 0; k < 16; ++k) s += validf[t * 16 + k];
    nvalidf[t] = s;
  }

  // ---- GEMM1: [128x256] @ W2[256x256], wave w -> cols [w*64, w*64+64) ----
  f32x4 zero4 = {0.f, 0.f, 0.f, 0.f};
  f32x4 acc[8][4];
#pragma unroll
  for (int i = 0; i < 8; ++i)
#pragma unroll
    for (int j = 0; j < 4; ++j) acc[i][j] = zero4;

  for (int kt = 0; kt < 8; ++kt) {
    s16x8 a[8];
#pragma unroll
    for (int rt = 0; rt < 8; ++rt) {
      int r = rt * 16 + lr;
      int off = (r * 512 + kt * 64 + lg * 16) ^ ((r & 7) << 4);
      a[rt] = *(const s16x8*)(h1b + off);
    }
#pragma unroll
    for (int ctl = 0; ctl < 4; ++ctl) {
      int ct = w * 4 + ctl;
      s16x8 bf = ld16(W2p + (((kt * 16 + ct) * 64) + l) * 8);
#pragma unroll
      for (int rt = 0; rt < 8; ++rt)
        acc[rt][ctl] = MFMA16(a[rt], bf, acc[rt][ctl]);
    }
  }

  // ---- epilogue: +b2, relu, mask, reduce 16 rows (one query per row-tile)
#pragma unroll
  for (int ctl = 0; ctl < 4; ++ctl) {
    int col = w * 64 + ctl * 16 + lr;
    float bias = b2[col];
#pragma unroll
    for (int rt = 0; rt < 8; ++rt) {
      float s = 0.f;
#pragma unroll
      for (int reg = 0; reg < 4; ++reg) {
        float v = fmaxf(acc[rt][ctl][reg] + bias, 0.f);
        s += v * validf[rt * 16 + lg * 4 + reg];
      }
      s += __shfl_xor(s, 16);
      s += __shfl_xor(s, 32);
      if (l < 16) {
        int off = (rt * 512 + col * 2) ^ ((rt & 7) << 4);
        *(unsigned short*)(gb + off) = f2bf(s);
      }
    }
  }
  __syncthreads();

  // ---- GEMM3: g[16x256] @ W3[256x128], wave w -> cols [w*32, w*32+32) ----
  f32x4 acc3[2];
  acc3[0] = zero4;
  acc3[1] = zero4;
  for (int kt = 0; kt < 8; ++kt) {
    int off = (lr * 512 + kt * 64 + lg * 16) ^ ((lr & 7) << 4);
    s16x8 a = *(const s16x8*)(gb + off);
#pragma unroll
    for (int ctl = 0; ctl < 2; ++ctl) {
      int ct = w * 2 + ctl;
      s16x8 bf = ld16(W3p + (((kt * 8 + ct) * 64) + l) * 8);
      acc3[ctl] = MFMA16(a, bf, acc3[ctl]);
    }
  }
#pragma unroll
  for (int ctl = 0; ctl < 2; ++ctl) {
    int col = w * 32 + ctl * 16 + lr;
    float bias = b3[col];
#pragma unroll
    for (int reg = 0; reg < 4; ++reg) {
      int q = lg * 4 + reg;             // row = query (valid 0..7)
      if (q < 8)
        out[(qbase + q) * Cc + col] = acc3[ctl][reg] + nvalidf[q] * bias;
    }
  }
}

// ---------------------------------------------------------------------------
extern "C" void kernel_launch(void* const* d_in, const int* in_sizes, int n_in,
                              void* d_out, int out_size, void* d_ws, size_t ws_size,
                              hipStream_t stream) {
  // setup_inputs order: keys(0) points(1) feats(2) n_idxs(3) neighbor_valid(4)
  //                     W1(5) b1(6) W2(7) b2(8) W3(9) b3(10)
  const float* feats = (const float*)d_in[2];
  const int* n_idxs = (const int*)d_in[3];
  const int* valid = (const int*)d_in[4];
  const float* W1 = (const float*)d_in[5];
  const float* b1 = (const float*)d_in[6];
  const float* W2 = (const float*)d_in[7];
  const float* b2 = (const float*)d_in[8];
  const float* W3 = (const float*)d_in[9];
  const float* b3 = (const float*)d_in[10];
  float* out = (float*)d_out;

  char* ws = (char*)d_ws;
  unsigned short* A_ws   = (unsigned short*)(ws);                          // 8 MB
  unsigned short* B_ws   = (unsigned short*)(ws + (8u << 20));             // 8 MB
  unsigned short* featsb = (unsigned short*)(ws + (16u << 20));            // 4 MB
  unsigned short* W1p    = (unsigned short*)(ws + (20u << 20));            // 128 KB
  unsigned short* W2p    = (unsigned short*)(ws + (20u << 20) + (128u << 10)); // 128 KB
  unsigned short* W3p    = (unsigned short*)(ws + (20u << 20) + (256u << 10)); // 64 KB

  pack_kernel<<<1104, 256, 0, stream>>>(feats, W1, W2, W3, featsb, W1p, W2p, W3p);
  k1_gemm<<<256, 256, 0, stream>>>(featsb, W1p, b1, A_ws, B_ws);
  k2_fused<<<2048, 256, 0, stream>>>(A_ws, B_ws, W2p, W3p, n_idxs, valid, b2, b3, out);
}